// Round 11
// baseline (223.782 us; speedup 1.0000x reference)
//
#include <hip/hip_runtime.h>
#include <hip/hip_bf16.h>
#include <math.h>

typedef float f32x4 __attribute__((ext_vector_type(4)));
typedef short short8 __attribute__((ext_vector_type(8)));

#define GEPS 1e-6f

static __device__ __forceinline__ short8 ldb8(const unsigned short* p) {
  return *reinterpret_cast<const short8*>(p);
}

static __device__ __forceinline__ void bfsplit(float v, unsigned short& h, unsigned short& l) {
  __hip_bfloat16 hb = __float2bfloat16(v);
  h = *reinterpret_cast<unsigned short*>(&hb);
  float r = v - __bfloat162float(hb);
  __hip_bfloat16 lb = __float2bfloat16(r);
  l = *reinterpret_cast<unsigned short*>(&lb);
}

// ---------------------------------------------------------------------------
// Kernel 1 (vectorized): block n, 256 thr. thread = (mq=tid>>6, c4=tid&63).
// Thread loads f4 x[m][c4*4..+3] for its 8 m's (kept in regs), writes packed
// ushort4 hi/lo bf16 splits, accumulates f4 col-partials. Cross-wave col sums
// via LDS; stats via algebra: a2=(Sxs-a1)/31, a3=(S2-2Sxs+a1)/961.
// ---------------------------------------------------------------------------
__global__ __launch_bounds__(256) void k1_prep(
    const float* __restrict__ x,
    unsigned short* __restrict__ xhg, unsigned short* __restrict__ xlg,
    unsigned short* __restrict__ chg, unsigned short* __restrict__ clg,
    float* __restrict__ invcn, float* __restrict__ xn, float* __restrict__ dsim)
{
  const int n = blockIdx.x;
  const int tid = threadIdx.x;
  const int c4 = tid & 63;          // column group: cols c4*4..c4*4+3
  const int mq = tid >> 6;          // wave: m's mq*8..mq*8+7
  __shared__ f32x4 part[4][64];

  f32x4 xr[8];
  f32x4 ps = (f32x4){0.f, 0.f, 0.f, 0.f};
  const size_t nbase = (size_t)n * 8192;

  #pragma unroll
  for (int p = 0; p < 8; ++p) {
    const int m = mq * 8 + p;
    const size_t off = nbase + m * 256 + c4 * 4;
    f32x4 v = *reinterpret_cast<const f32x4*>(x + off);
    xr[p] = v;
    ps += v;
    ushort4 hv, lv;
    bfsplit(v.x, hv.x, lv.x);
    bfsplit(v.y, hv.y, lv.y);
    bfsplit(v.z, hv.z, lv.z);
    bfsplit(v.w, hv.w, lv.w);
    *reinterpret_cast<ushort4*>(xhg + off) = hv;
    *reinterpret_cast<ushort4*>(xlg + off) = lv;
  }
  part[mq][c4] = ps;
  __syncthreads();

  // full column sums sl (4 cols per thread), redundantly in every wave
  f32x4 sl = part[0][c4] + part[1][c4] + part[2][c4] + part[3][c4];

  // centroid write (wave 0 only)
  if (mq == 0) {
    f32x4 c = sl * 0.03125f;
    ushort4 hv, lv;
    bfsplit(c.x, hv.x, lv.x);
    bfsplit(c.y, hv.y, lv.y);
    bfsplit(c.z, hv.z, lv.z);
    bfsplit(c.w, hv.w, lv.w);
    *reinterpret_cast<ushort4*>(chg + n * 256 + c4 * 4) = hv;
    *reinterpret_cast<ushort4*>(clg + n * 256 + c4 * 4) = lv;
  }

  // S2 = sum_d sl[d]^2 (all lanes end with the value via xor-reduce)
  float s2 = sl.x * sl.x + sl.y * sl.y + sl.z * sl.z + sl.w * sl.w;
  #pragma unroll
  for (int off = 32; off; off >>= 1) s2 += __shfl_xor(s2, off, 64);
  if (tid == 0) invcn[n] = 32.0f / sqrtf(s2);   // 1/||cent||, cn^2 = S2/1024

  // per-m stats: a1 = sum x^2, Sxs = sum x*sl
  #pragma unroll
  for (int p = 0; p < 8; ++p) {
    const f32x4 v = xr[p];
    float a1 = v.x * v.x + v.y * v.y + v.z * v.z + v.w * v.w;
    float sx = v.x * sl.x + v.y * sl.y + v.z * sl.z + v.w * sl.w;
    #pragma unroll
    for (int off = 32; off; off >>= 1) {
      a1 += __shfl_xor(a1, off, 64);
      sx += __shfl_xor(sx, off, 64);
    }
    if (c4 == 0) {
      const int m = mq * 8 + p;
      const float a2 = (sx - a1) * (1.0f / 31.0f);
      const float a3 = (s2 - 2.0f * sx + a1) * (1.0f / 961.0f);
      const float xnv = sqrtf(a1);
      const float mn  = sqrtf(a3);
      xn[n * 32 + m]   = xnv;
      dsim[n * 32 + m] = a2 / fmaxf(xnv * mn, GEPS);
    }
  }
}

// ---------------------------------------------------------------------------
// Kernel 2: bf16-split MFMA dots + fixed-bound partial sum-exp.
// 2048 blocks x 256 thr: block = 64 rows (rowbase=(bid>>2)*64) x 256 cols
// (quarter cq=bid&3). Wave wv -> 64-col tile at cq*256+wv*64. acc[4 mt][4 kt]
// (64 AGPR). Pass-outer MFMA order: dependent-chain distance 16.
// Partial rowsums -> LDS rs[64] -> global atomicAdd(rowsum).
// ---------------------------------------------------------------------------
__global__ __launch_bounds__(256, 3) void k2_mfma(
    const unsigned short* __restrict__ xhg, const unsigned short* __restrict__ xlg,
    const unsigned short* __restrict__ chg, const unsigned short* __restrict__ clg,
    const float* __restrict__ invcn, const float* __restrict__ xn,
    const float* __restrict__ dsim, const float* __restrict__ wp,
    const float* __restrict__ bp, float* __restrict__ row_sum)
{
  const int bid = blockIdx.x;
  const int rowbase = (bid >> 2) * 64;
  const int cq = bid & 3;
  const int tid = threadIdx.x;
  const int wv = tid >> 6;
  const int lane = tid & 63;
  const int q = lane >> 4;
  const int l15 = lane & 15;
  const int colbase = cq * 256 + wv * 64;

  __shared__ float rs[64];
  if (tid < 64) rs[tid] = 0.f;
  __syncthreads();

  f32x4 acc[4][4];
  #pragma unroll
  for (int mt = 0; mt < 4; ++mt)
    #pragma unroll
    for (int kt = 0; kt < 4; ++kt) acc[mt][kt] = (f32x4){0.f, 0.f, 0.f, 0.f};

  #pragma unroll 1
  for (int ck = 0; ck < 8; ++ck) {
    const int d0 = ck * 32 + q * 8;
    short8 a_h[4], a_l[4], b_h[4], b_l[4];
    #pragma unroll
    for (int mt = 0; mt < 4; ++mt) {
      const size_t abase = (size_t)(rowbase + mt * 16 + l15) * 256 + d0;
      a_h[mt] = ldb8(xhg + abase);
      a_l[mt] = ldb8(xlg + abase);
    }
    #pragma unroll
    for (int kt = 0; kt < 4; ++kt) {
      const size_t bbase = (size_t)(colbase + kt * 16 + l15) * 256 + d0;
      b_h[kt] = ldb8(chg + bbase);
      b_l[kt] = ldb8(clg + bbase);
    }
    // pass-outer: 16 independent MFMAs between reuses of any acc
    #pragma unroll
    for (int mt = 0; mt < 4; ++mt)
      #pragma unroll
      for (int kt = 0; kt < 4; ++kt)
        acc[mt][kt] = __builtin_amdgcn_mfma_f32_16x16x32_bf16(a_l[mt], b_h[kt], acc[mt][kt], 0, 0, 0);
    #pragma unroll
    for (int mt = 0; mt < 4; ++mt)
      #pragma unroll
      for (int kt = 0; kt < 4; ++kt)
        acc[mt][kt] = __builtin_amdgcn_mfma_f32_16x16x32_bf16(a_h[mt], b_l[kt], acc[mt][kt], 0, 0, 0);
    #pragma unroll
    for (int mt = 0; mt < 4; ++mt)
      #pragma unroll
      for (int kt = 0; kt < 4; ++kt)
        acc[mt][kt] = __builtin_amdgcn_mfma_f32_16x16x32_bf16(a_h[mt], b_h[kt], acc[mt][kt], 0, 0, 0);
  }

  const float w = wp[0], b = bp[0];
  const float B = fabsf(w) + fabsf(b);
  const float L2E = 1.44269504088896f;
  const float u = (b - B) * L2E;
  const float wl = w * L2E;

  // epilogue: per-row constants loaded here (not hoisted) to keep main-loop
  // register pressure low; 16-lane groups broadcast the same grow.
  #pragma unroll
  for (int mt = 0; mt < 4; ++mt) {
    const int nrow = (rowbase + mt * 16) >> 5;     // speaker for this m-tile
    #pragma unroll
    for (int r = 0; r < 4; ++r) {
      const int grow = rowbase + mt * 16 + q * 4 + r;
      const float srow = wl / xn[grow];
      const float ediag = fmaf(dsim[grow], wl, u);
      float S = 0.f;
      #pragma unroll
      for (int kt = 0; kt < 4; ++kt) {
        const int colg = colbase + kt * 16 + l15;
        float p = exp2f(fmaf(acc[mt][kt][r] * srow, invcn[colg], u));
        if (colg == nrow) p = exp2f(ediag);        // diagonal splice
        S += p;
      }
      S += __shfl_xor(S, 1, 64);
      S += __shfl_xor(S, 2, 64);
      S += __shfl_xor(S, 4, 64);
      S += __shfl_xor(S, 8, 64);
      if (l15 == 0) atomicAdd(&rs[mt * 16 + q * 4 + r], S);
    }
  }
  __syncthreads();
  if (tid < 64) atomicAdd(&row_sum[rowbase + tid], rs[tid]);
}

// ---------------------------------------------------------------------------
// Kernel 3: loss_i = -(w*dsim+b) + B + log(row_sum), summed into d_out.
// ---------------------------------------------------------------------------
__global__ __launch_bounds__(256) void k3_final(
    const float* __restrict__ dsim, const float* __restrict__ row_sum,
    const float* __restrict__ wp, const float* __restrict__ bp,
    float* __restrict__ out)
{
  const int r = blockIdx.x * 256 + threadIdx.x;   // 128 blocks -> 32768 rows
  const float w = wp[0], b = bp[0];
  const float B = fabsf(w) + fabsf(b);
  float v = -fmaf(w, dsim[r], b) + B + logf(row_sum[r]);
  #pragma unroll
  for (int off = 32; off; off >>= 1) v += __shfl_xor(v, off, 64);
  __shared__ float red[4];
  const int lane = threadIdx.x & 63, wv = threadIdx.x >> 6;
  if (lane == 0) red[wv] = v;
  __syncthreads();
  if (threadIdx.x == 0) atomicAdd(out, red[0] + red[1] + red[2] + red[3]);
}

// ---------------------------------------------------------------------------
extern "C" void kernel_launch(void* const* d_in, const int* in_sizes, int n_in,
                              void* d_out, int out_size, void* d_ws, size_t ws_size,
                              hipStream_t stream)
{
  const float* x = (const float*)d_in[0];
  const float* w = (const float*)d_in[1];
  const float* b = (const float*)d_in[2];
  float* out = (float*)d_out;

  char* W = (char*)d_ws;
  unsigned short* xhg = (unsigned short*)(W);                  // 16 MiB
  unsigned short* xlg = (unsigned short*)(W + 16777216);       // 16 MiB
  unsigned short* chg = (unsigned short*)(W + 33554432);       // 512 KiB
  unsigned short* clg = (unsigned short*)(W + 34078720);       // 512 KiB
  float* invcn  = (float*)(W + 34603008);                      // 4 KiB
  float* xn     = (float*)(W + 34607104);                      // 128 KiB
  float* dsim   = (float*)(W + 34738176);                      // 128 KiB
  float* rowsum = (float*)(W + 34869248);                      // 128 KiB

  hipMemsetAsync(rowsum, 0, 32768 * sizeof(float), stream);
  hipMemsetAsync(out, 0, sizeof(float), stream);
  k1_prep<<<1024, 256, 0, stream>>>(x, xhg, xlg, chg, clg, invcn, xn, dsim);
  k2_mfma<<<2048, 256, 0, stream>>>(xhg, xlg, chg, clg, invcn, xn, dsim, w, b, rowsum);
  k3_final<<<128, 256, 0, stream>>>(dsim, rowsum, w, b, out);
}

// Round 14
// 222.656 us; speedup vs baseline: 1.0051x; 1.0051x over previous
//
#include <hip/hip_runtime.h>
#include <hip/hip_bf16.h>
#include <math.h>

typedef float f32x4 __attribute__((ext_vector_type(4)));
typedef short short8 __attribute__((ext_vector_type(8)));
typedef unsigned short ushort8v __attribute__((ext_vector_type(8)));

#define GEPS 1e-6f

static __device__ __forceinline__ short8 ldb8(const unsigned short* p) {
  return *reinterpret_cast<const short8*>(p);
}

static __device__ __forceinline__ void bfsplit(float v, unsigned short& h, unsigned short& l) {
  __hip_bfloat16 hb = __float2bfloat16(v);
  h = *reinterpret_cast<unsigned short*>(&hb);
  float r = v - __bfloat162float(hb);
  __hip_bfloat16 lb = __float2bfloat16(r);
  l = *reinterpret_cast<unsigned short*>(&lb);
}

// ---------------------------------------------------------------------------
// Kernel 1: per-speaker prep, 16B-store layout. block n, 256 thr.
// thread = (mrow=tid>>5 in 0..7, dg=tid&31 -> d = dg*8..dg*8+7).
// Each thread handles m = mi*8+mrow (mi=0..3): loads 2*f32x4 (32B), writes
// ushort8 hi/lo (16B each). Column sums via LDS part[2][8][32]; stats via
// algebra (a2=(Sxs-a1)/31, a3=(S2-2Sxs+a1)/961) with 32-lane-half reduces.
// ---------------------------------------------------------------------------
__global__ __launch_bounds__(256) void k1_prep(
    const float* __restrict__ x,
    unsigned short* __restrict__ xhg, unsigned short* __restrict__ xlg,
    unsigned short* __restrict__ chg, unsigned short* __restrict__ clg,
    float* __restrict__ invcn, float* __restrict__ xn, float* __restrict__ dsim)
{
  const int n = blockIdx.x;
  const int tid = threadIdx.x;
  const int dg = tid & 31;
  const int mrow = tid >> 5;
  __shared__ f32x4 part[2][8][32];

  const size_t nbase = (size_t)n * 8192;
  f32x4 xa0[4], xa1[4];
  f32x4 ps0 = (f32x4){0.f,0.f,0.f,0.f}, ps1 = (f32x4){0.f,0.f,0.f,0.f};

  #pragma unroll
  for (int mi = 0; mi < 4; ++mi) {
    const int m = mi * 8 + mrow;
    const size_t off = nbase + m * 256 + dg * 8;
    f32x4 v0 = *reinterpret_cast<const f32x4*>(x + off);
    f32x4 v1 = *reinterpret_cast<const f32x4*>(x + off + 4);
    xa0[mi] = v0; xa1[mi] = v1;
    ps0 += v0; ps1 += v1;
    ushort8v hv, lv;
    #pragma unroll
    for (int e = 0; e < 4; ++e) {
      unsigned short h, l;
      bfsplit(v0[e], h, l); hv[e] = h; lv[e] = l;
    }
    #pragma unroll
    for (int e = 0; e < 4; ++e) {
      unsigned short h, l;
      bfsplit(v1[e], h, l); hv[4+e] = h; lv[4+e] = l;
    }
    *reinterpret_cast<ushort8v*>(xhg + off) = hv;
    *reinterpret_cast<ushort8v*>(xlg + off) = lv;
  }
  part[0][mrow][dg] = ps0;
  part[1][mrow][dg] = ps1;
  __syncthreads();

  f32x4 sl0 = (f32x4){0.f,0.f,0.f,0.f}, sl1 = (f32x4){0.f,0.f,0.f,0.f};
  #pragma unroll
  for (int mr = 0; mr < 8; ++mr) { sl0 += part[0][mr][dg]; sl1 += part[1][mr][dg]; }

  // centroid hi/lo (lanes 0..31 of wave 0 cover all 256 d)
  if (tid < 32) {
    f32x4 c0 = sl0 * 0.03125f, c1 = sl1 * 0.03125f;
    ushort8v hv, lv;
    #pragma unroll
    for (int e = 0; e < 4; ++e) {
      unsigned short h, l;
      bfsplit(c0[e], h, l); hv[e] = h; lv[e] = l;
    }
    #pragma unroll
    for (int e = 0; e < 4; ++e) {
      unsigned short h, l;
      bfsplit(c1[e], h, l); hv[4+e] = h; lv[4+e] = l;
    }
    *reinterpret_cast<ushort8v*>(chg + n * 256 + dg * 8) = hv;
    *reinterpret_cast<ushort8v*>(clg + n * 256 + dg * 8) = lv;
  }

  // S2 = sum_d sl^2 (each 32-lane half spans dg=0..31 -> full 256-d sum)
  float s2 = sl0.x*sl0.x + sl0.y*sl0.y + sl0.z*sl0.z + sl0.w*sl0.w
           + sl1.x*sl1.x + sl1.y*sl1.y + sl1.z*sl1.z + sl1.w*sl1.w;
  #pragma unroll
  for (int off = 16; off; off >>= 1) s2 += __shfl_xor(s2, off, 64);
  if (tid == 0) invcn[n] = 32.0f / sqrtf(s2);

  // per-m stats
  #pragma unroll
  for (int mi = 0; mi < 4; ++mi) {
    const f32x4 v0 = xa0[mi], v1 = xa1[mi];
    float a1 = v0.x*v0.x + v0.y*v0.y + v0.z*v0.z + v0.w*v0.w
             + v1.x*v1.x + v1.y*v1.y + v1.z*v1.z + v1.w*v1.w;
    float sx = v0.x*sl0.x + v0.y*sl0.y + v0.z*sl0.z + v0.w*sl0.w
             + v1.x*sl1.x + v1.y*sl1.y + v1.z*sl1.z + v1.w*sl1.w;
    #pragma unroll
    for (int off = 16; off; off >>= 1) {
      a1 += __shfl_xor(a1, off, 64);
      sx += __shfl_xor(sx, off, 64);
    }
    if (dg == 0) {
      const int m = mi * 8 + mrow;
      const float a2 = (sx - a1) * (1.0f / 31.0f);
      const float a3 = (s2 - 2.0f * sx + a1) * (1.0f / 961.0f);
      const float xnv = sqrtf(a1);
      const float mn  = sqrtf(a3);
      xn[n * 32 + m]   = xnv;
      dsim[n * 32 + m] = a2 / fmaxf(xnv * mn, GEPS);
    }
  }
}

// ---------------------------------------------------------------------------
// Kernel 2: bf16-split MFMA dots + fixed-bound partial sum-exp.
// 2048 blocks x 256 thr. XCD-bijective remap (physical xcd = bid&7 assumed):
// all 4 col-quarters of a row-group on one XCD -> A panel fetched once/XCD.
// Register double-buffer: 16 fragment loads for ck+1 issued before the 48
// MFMAs of ck (named A/B buffers, no runtime indexing).
// ---------------------------------------------------------------------------
__global__ __launch_bounds__(256, 2) void k2_mfma(
    const unsigned short* __restrict__ xhg, const unsigned short* __restrict__ xlg,
    const unsigned short* __restrict__ chg, const unsigned short* __restrict__ clg,
    const float* __restrict__ invcn, const float* __restrict__ xn,
    const float* __restrict__ dsim, const float* __restrict__ wp,
    const float* __restrict__ bp, float* __restrict__ row_sum)
{
  const int bid = blockIdx.x;
  const int xcd = bid & 7;
  const int slot = bid >> 3;
  const int rgrp = xcd + 8 * (slot >> 2);    // 0..511, bijective
  const int cq = slot & 3;
  const int rowbase = rgrp * 64;
  const int tid = threadIdx.x;
  const int wv = tid >> 6;
  const int lane = tid & 63;
  const int q = lane >> 4;
  const int l15 = lane & 15;
  const int colbase = cq * 256 + wv * 64;

  __shared__ float rs[64];
  if (tid < 64) rs[tid] = 0.f;
  __syncthreads();

  size_t abase[4], bbase[4];
  #pragma unroll
  for (int mt = 0; mt < 4; ++mt)
    abase[mt] = (size_t)(rowbase + mt * 16 + l15) * 256 + q * 8;
  #pragma unroll
  for (int kt = 0; kt < 4; ++kt)
    bbase[kt] = (size_t)(colbase + kt * 16 + l15) * 256 + q * 8;

  f32x4 acc[4][4];
  #pragma unroll
  for (int mt = 0; mt < 4; ++mt)
    #pragma unroll
    for (int kt = 0; kt < 4; ++kt) acc[mt][kt] = (f32x4){0.f,0.f,0.f,0.f};

  auto LOAD = [&](int ck, short8 (&ah)[4], short8 (&al)[4],
                  short8 (&bh)[4], short8 (&bl)[4]) {
    const int off = ck * 32;
    #pragma unroll
    for (int mt = 0; mt < 4; ++mt) {
      ah[mt] = ldb8(xhg + abase[mt] + off);
      al[mt] = ldb8(xlg + abase[mt] + off);
    }
    #pragma unroll
    for (int kt = 0; kt < 4; ++kt) {
      bh[kt] = ldb8(chg + bbase[kt] + off);
      bl[kt] = ldb8(clg + bbase[kt] + off);
    }
  };
  auto MFMA3 = [&](short8 (&ah)[4], short8 (&al)[4],
                   short8 (&bh)[4], short8 (&bl)[4]) {
    #pragma unroll
    for (int mt = 0; mt < 4; ++mt)
      #pragma unroll
      for (int kt = 0; kt < 4; ++kt)
        acc[mt][kt] = __builtin_amdgcn_mfma_f32_16x16x32_bf16(al[mt], bh[kt], acc[mt][kt], 0, 0, 0);
    #pragma unroll
    for (int mt = 0; mt < 4; ++mt)
      #pragma unroll
      for (int kt = 0; kt < 4; ++kt)
        acc[mt][kt] = __builtin_amdgcn_mfma_f32_16x16x32_bf16(ah[mt], bl[kt], acc[mt][kt], 0, 0, 0);
    #pragma unroll
    for (int mt = 0; mt < 4; ++mt)
      #pragma unroll
      for (int kt = 0; kt < 4; ++kt)
        acc[mt][kt] = __builtin_amdgcn_mfma_f32_16x16x32_bf16(ah[mt], bh[kt], acc[mt][kt], 0, 0, 0);
  };

  short8 ahA[4], alA[4], bhA[4], blA[4];
  short8 ahB[4], alB[4], bhB[4], blB[4];
  LOAD(0, ahA, alA, bhA, blA);
  #pragma unroll 1
  for (int t = 0; t < 4; ++t) {
    LOAD(2 * t + 1, ahB, alB, bhB, blB);   // prefetch odd chunk
    MFMA3(ahA, alA, bhA, blA);             // compute even chunk
    if (t < 3) LOAD(2 * t + 2, ahA, alA, bhA, blA);  // prefetch next even
    MFMA3(ahB, alB, bhB, blB);             // compute odd chunk
  }

  const float w = wp[0], b = bp[0];
  const float B = fabsf(w) + fabsf(b);
  const float L2E = 1.44269504088896f;
  const float u = (b - B) * L2E;
  const float wl = w * L2E;

  #pragma unroll
  for (int mt = 0; mt < 4; ++mt) {
    const int nrow = (rowbase + mt * 16) >> 5;     // speaker for this m-tile
    #pragma unroll
    for (int r = 0; r < 4; ++r) {
      const int grow = rowbase + mt * 16 + q * 4 + r;
      const float srow = wl / xn[grow];
      const float ediag = fmaf(dsim[grow], wl, u);
      float S = 0.f;
      #pragma unroll
      for (int kt = 0; kt < 4; ++kt) {
        const int colg = colbase + kt * 16 + l15;
        float p = exp2f(fmaf(acc[mt][kt][r] * srow, invcn[colg], u));
        if (colg == nrow) p = exp2f(ediag);        // diagonal splice
        S += p;
      }
      S += __shfl_xor(S, 1, 64);
      S += __shfl_xor(S, 2, 64);
      S += __shfl_xor(S, 4, 64);
      S += __shfl_xor(S, 8, 64);
      if (l15 == 0) atomicAdd(&rs[mt * 16 + q * 4 + r], S);
    }
  }
  __syncthreads();
  if (tid < 64) atomicAdd(&row_sum[rowbase + tid], rs[tid]);
}

// ---------------------------------------------------------------------------
// Kernel 3: loss_i = -(w*dsim+b) + B + log(row_sum), summed into d_out.
// ---------------------------------------------------------------------------
__global__ __launch_bounds__(256) void k3_final(
    const float* __restrict__ dsim, const float* __restrict__ row_sum,
    const float* __restrict__ wp, const float* __restrict__ bp,
    float* __restrict__ out)
{
  const int r = blockIdx.x * 256 + threadIdx.x;   // 128 blocks -> 32768 rows
  const float w = wp[0], b = bp[0];
  const float B = fabsf(w) + fabsf(b);
  float v = -fmaf(w, dsim[r], b) + B + logf(row_sum[r]);
  #pragma unroll
  for (int off = 32; off; off >>= 1) v += __shfl_xor(v, off, 64);
  __shared__ float red[4];
  const int lane = threadIdx.x & 63, wv = threadIdx.x >> 6;
  if (lane == 0) red[wv] = v;
  __syncthreads();
  if (threadIdx.x == 0) atomicAdd(out, red[0] + red[1] + red[2] + red[3]);
}

// ---------------------------------------------------------------------------
extern "C" void kernel_launch(void* const* d_in, const int* in_sizes, int n_in,
                              void* d_out, int out_size, void* d_ws, size_t ws_size,
                              hipStream_t stream)
{
  const float* x = (const float*)d_in[0];
  const float* w = (const float*)d_in[1];
  const float* b = (const float*)d_in[2];
  float* out = (float*)d_out;

  char* W = (char*)d_ws;
  unsigned short* xhg = (unsigned short*)(W);                  // 16 MiB
  unsigned short* xlg = (unsigned short*)(W + 16777216);       // 16 MiB
  unsigned short* chg = (unsigned short*)(W + 33554432);       // 512 KiB
  unsigned short* clg = (unsigned short*)(W + 34078720);       // 512 KiB
  float* invcn  = (float*)(W + 34603008);                      // 4 KiB
  float* xn     = (float*)(W + 34607104);                      // 128 KiB
  float* dsim   = (float*)(W + 34738176);                      // 128 KiB
  float* rowsum = (float*)(W + 34869248);                      // 128 KiB

  hipMemsetAsync(rowsum, 0, 32768 * sizeof(float), stream);
  hipMemsetAsync(out, 0, sizeof(float), stream);
  k1_prep<<<1024, 256, 0, stream>>>(x, xhg, xlg, chg, clg, invcn, xn, dsim);
  k2_mfma<<<2048, 256, 0, stream>>>(xhg, xlg, chg, clg, invcn, xn, dsim, w, b, rowsum);
  k3_final<<<128, 256, 0, stream>>>(dsim, rowsum, w, b, out);
}